// Round 11
// baseline (80.223 us; speedup 1.0000x reference)
//
#include <hip/hip_runtime.h>

// LocNet2d on MFMA fp16, global_load_lds staging + counted-vmcnt (T4) pipeline.
// L1: per-s2-cell GEMM over 16 patches, LDS-transposed epilogue -> coalesced
//     A2 fp16 [s][b][k2=o*16+g] writes.
// L2: per-s GEMM M=128,N=512,K=8192, splitK=16, K-step=64, LDS dbuf, vmcnt(8).
// reduce2: float4 over (kc,s), coalesced 32-B A3 writes.
// L3: same gemm structure, K=2048, splitK=16 -> P3 -> fused reduce+head.

typedef _Float16 f16;
typedef _Float16 half8 __attribute__((ext_vector_type(8)));
typedef _Float16 half4 __attribute__((ext_vector_type(4)));
typedef float f32x4 __attribute__((ext_vector_type(4)));

#define SWZ(r, c) ((((r) << 6) + (c)) ^ (((r) & 7) << 3))

#define GLOAD_LDS16(G, L)                                                     \
  __builtin_amdgcn_global_load_lds(                                           \
      (const __attribute__((address_space(1))) void*)(G),                     \
      (__attribute__((address_space(3))) void*)(L), 16, 0, 0)

__global__ __launch_bounds__(256) void l1_mfma(const float* __restrict__ x,
                                               const float* __restrict__ w1,
                                               f16* __restrict__ A2) {
  // grid (8 o-tiles, 4 s2-cells, 2 b-halves); block 256 = 4 waves (2b x 2o of 32x32).
  const int ot = blockIdx.x, s2 = blockIdx.y, bt = blockIdx.z;
  const int p2 = s2 >> 1, q2 = s2 & 1;
  const int o0 = ot << 6, b0 = bt << 6;
  __shared__ __align__(16) f16 Xs[64 * 64];   // 8 KB, [b][k] k=c*16+fi*4+fj (pad 48..63)
  __shared__ __align__(16) f16 Ws[64 * 64];   // 8 KB, [o][k]
  __shared__ __align__(16) f16 Yb[64 * 512];  // 64 KB, [b][olocal*8+gl]
  const int t = threadIdx.x;
  const int wv = t >> 6, ln = t & 63;
  const int bw = wv >> 1, ow = wv & 1;
  const int frow = ln & 15, fr4 = ln >> 4;
  f16* A2b = A2 + (size_t)s2 * 128 * 8192;

  for (int gb = 0; gb < 2; ++gb) {
    for (int gl = 0; gl < 8; ++gl) {
      const int g = gb * 8 + gl;
      const int p1 = p2 * 4 + (g >> 2), q1 = q2 * 4 + (g & 3);
#pragma unroll
      for (int i = 0; i < 4; ++i) {  // stage Xs: 64 rows x 16 half4-chunks
        int idx = (i << 8) + t, row = idx >> 4, j = idx & 15;
        half4 h = {0, 0, 0, 0};
        if (j < 12) {
          float4 v = *(const float4*)(x + ((size_t)(b0 + row) * 3 + (j >> 2)) * 1024 +
                                      (p1 * 4 + (j & 3)) * 32 + q1 * 4);
          h[0] = (f16)v.x; h[1] = (f16)v.y; h[2] = (f16)v.z; h[3] = (f16)v.w;
        }
        *(half4*)&Xs[SWZ(row, j << 2)] = h;
      }
#pragma unroll
      for (int i = 0; i < 4; ++i) {  // stage Ws
        int idx = (i << 8) + t, row = idx >> 4, j = idx & 15;
        half4 h = {0, 0, 0, 0};
        if (j < 12) {
          float4 v = *(const float4*)(w1 + (size_t)(o0 + row) * 3072 + (j >> 2) * 1024 +
                                      p1 * 128 + q1 * 16 + (j & 3) * 4);
          h[0] = (f16)v.x; h[1] = (f16)v.y; h[2] = (f16)v.z; h[3] = (f16)v.w;
        }
        *(half4*)&Ws[SWZ(row, j << 2)] = h;
      }
      __syncthreads();
      f32x4 acc[2][2] = {};
#pragma unroll
      for (int ks = 0; ks < 2; ++ks) {
        const int col = (ks << 5) + (fr4 << 3);
        half8 a[2], b[2];
#pragma unroll
        for (int mi = 0; mi < 2; ++mi)
          a[mi] = *(const half8*)&Xs[SWZ(bw * 32 + mi * 16 + frow, col)];
#pragma unroll
        for (int ni = 0; ni < 2; ++ni)
          b[ni] = *(const half8*)&Ws[SWZ(ow * 32 + ni * 16 + frow, col)];
#pragma unroll
        for (int mi = 0; mi < 2; ++mi)
#pragma unroll
          for (int ni = 0; ni < 2; ++ni)
            acc[mi][ni] = __builtin_amdgcn_mfma_f32_16x16x32_f16(a[mi], b[ni], acc[mi][ni], 0, 0, 0);
      }
      // epilogue: relu/scale -> Yb[b][olocal*8+gl]
#pragma unroll
      for (int mi = 0; mi < 2; ++mi)
#pragma unroll
        for (int ni = 0; ni < 2; ++ni)
#pragma unroll
          for (int r = 0; r < 4; ++r) {
            int gm = bw * 32 + mi * 16 + fr4 * 4 + r;
            int gn = ow * 32 + ni * 16 + frow;
            float v = fmaxf(acc[mi][ni][r] * 0.14433756729740643f, 0.f);  // 1/sqrt(48)
            Yb[gm * 512 + gn * 8 + gl] = (f16)v;
          }
      __syncthreads();  // Yb writes done; safe to re-stage Xs/Ws next patch
    }
    // flush Yb -> A2 (coalesced 16-B stores): thread t -> b=t>>2, q=t&3
    {
      const int b = t >> 2, q = t & 3;
#pragma unroll
      for (int j = 0; j < 16; ++j) {
        int c = q * 16 + j;  // olocal 0..63
        half8 v = *(const half8*)&Yb[b * 512 + c * 8];
        *(half8*)(A2b + (size_t)(b0 + b) * 8192 + (o0 + c) * 16 + gb * 8) = v;
      }
    }
    __syncthreads();  // flush reads done before next batch overwrites Yb
  }
}

// MODE 0: L2 (w2 fp32 s-gather, 512 blocks). MODE 1: L3 (w3 fp32 contiguous, 128 blocks).
// Tile M=128 x N=64, K-step 64, double-buffered LDS, counted-vmcnt pipeline. (R8 config)
template <int MODE>
__global__ __launch_bounds__(256) void gemm_f16(const f16* __restrict__ A,
                                                const float* __restrict__ W,
                                                float* __restrict__ P) {
  __shared__ __align__(16) f16 As[2][128 * 64];   // 2 x 16 KB
  __shared__ __align__(16) float Bs[2][64 * 64];  // 2 x 16 KB
  const int t = threadIdx.x;
  const int bid = blockIdx.x;
  constexpr int AK = (MODE == 0) ? 8192 : 2048;
  constexpr int ITERS = (MODE == 0) ? 8 : 2;  // K-chunk 512 / 128, step 64
  // MODE 0: bid = s*128 + kc*8 + n. MODE 1: bid = kc*8 + n.
  const int s = (MODE == 0) ? (bid >> 7) : 0;
  const int kc = (MODE == 0) ? ((bid >> 3) & 15) : (bid >> 3);
  const int n = bid & 7;
  const int kb0 = kc * (ITERS * 64);
  const f16* Ab = A + (size_t)(MODE == 0 ? s * 128 : 0) * AK + kb0;
  const int o0 = n << 6;

  const int wv = t >> 6, ln = t & 63;
  const int a_r = (ln >> 3), a_sg0 = ln & 7;
  const int b_r = (ln >> 4), b_sg0 = ln & 15;

#define STAGE(IT, BUF)                                                          \
  {                                                                             \
    _Pragma("unroll") for (int jj = 0; jj < 4; ++jj) {                          \
      int rbase = wv * 32 + jj * 8;                                             \
      int r = rbase + a_r;                                                      \
      int sg = a_sg0 ^ (r & 7);                                                 \
      GLOAD_LDS16(Ab + (size_t)r * AK + ((IT) << 6) + (sg << 3),                \
                  &As[BUF][rbase << 6]);                                        \
    }                                                                           \
    _Pragma("unroll") for (int jj = 0; jj < 4; ++jj) {                          \
      int rbase = wv * 16 + jj * 4;                                             \
      int r = rbase + b_r;                                                      \
      int sg = b_sg0 ^ (r & 7);                                                 \
      const float* gp;                                                          \
      if constexpr (MODE == 0) {                                                \
        int k = kb0 + ((IT) << 6) + (sg << 2);                                  \
        gp = W + (size_t)(o0 + r) * 32768 + ((k >> 4) << 6) + (s << 4) + (k & 15); \
      } else {                                                                  \
        gp = W + (size_t)(o0 + r) * 2048 + kb0 + ((IT) << 6) + (sg << 2);       \
      }                                                                         \
      GLOAD_LDS16(gp, &Bs[BUF][rbase << 6]);                                    \
    }                                                                           \
  }

  const int wr = wv >> 1, wc = wv & 1;
  const int frow = ln & 15, fr4 = ln >> 4;
  f32x4 acc[4][2] = {};

#define COMPUTE(BUF)                                                            \
  _Pragma("unroll") for (int ks = 0; ks < 2; ++ks) {                            \
    half8 a[4];                                                                 \
    _Pragma("unroll") for (int mi = 0; mi < 4; ++mi) {                          \
      int r = wr * 64 + mi * 16 + frow;                                         \
      int gl = ((ks << 2) + fr4) ^ (r & 7);                                     \
      a[mi] = *(const half8*)&As[BUF][(r << 6) + (gl << 3)];                    \
    }                                                                           \
    _Pragma("unroll") for (int ni = 0; ni < 2; ++ni) {                          \
      int r = wc * 32 + ni * 16 + frow;                                         \
      int s0 = (ks << 3) + (fr4 << 1);                                          \
      float4 f0 = *(const float4*)&Bs[BUF][(r << 6) + ((s0 ^ (r & 7)) << 2)];   \
      float4 f1 = *(const float4*)&Bs[BUF][(r << 6) + (((s0 + 1) ^ (r & 7)) << 2)]; \
      half8 hb;                                                                 \
      hb[0] = (f16)f0.x; hb[1] = (f16)f0.y; hb[2] = (f16)f0.z; hb[3] = (f16)f0.w; \
      hb[4] = (f16)f1.x; hb[5] = (f16)f1.y; hb[6] = (f16)f1.z; hb[7] = (f16)f1.w; \
      _Pragma("unroll") for (int mi = 0; mi < 4; ++mi)                          \
        acc[mi][ni] = __builtin_amdgcn_mfma_f32_16x16x32_f16(a[mi], hb, acc[mi][ni], 0, 0, 0); \
    }                                                                           \
  }

  STAGE(0, 0)
#pragma unroll
  for (int it = 0; it < ITERS; ++it) {
    const int cur = it & 1;
    if (it + 1 < ITERS) {
      STAGE(it + 1, cur ^ 1)  // 8 more in flight (16 total)
      asm volatile("s_waitcnt vmcnt(8)" ::: "memory");  // cur's 8 landed
    } else {
      asm volatile("s_waitcnt vmcnt(0)" ::: "memory");  // last tile: full drain
    }
    __builtin_amdgcn_s_barrier();       // all waves see cur tile in LDS
    __builtin_amdgcn_sched_barrier(0);  // rule 18: no hoist above the wait
    COMPUTE(cur)
    __builtin_amdgcn_sched_barrier(0);
    __builtin_amdgcn_s_barrier();       // all reads done before cur is re-staged
  }

  float* Pb = P + (size_t)(MODE == 0 ? (kc << 2) + s : kc) * 65536;
#pragma unroll
  for (int mi = 0; mi < 4; ++mi)
#pragma unroll
    for (int ni = 0; ni < 2; ++ni)
#pragma unroll
      for (int r = 0; r < 4; ++r) {
        int gm = wr * 64 + mi * 16 + fr4 * 4 + r;
        int gn = o0 + wc * 32 + ni * 16 + frow;
        Pb[(size_t)gm * 512 + gn] = acc[mi][ni][r];
      }
#undef STAGE
#undef COMPUTE
}

__global__ __launch_bounds__(256) void reduce2(const float* __restrict__ P2,
                                               f16* __restrict__ A3) {
  // 16384 threads: thread -> (b, og); handles 4 o x 4 s -> one 32-B A3 chunk.
  int idx = blockIdx.x * 256 + threadIdx.x;
  int og = idx & 127, b = idx >> 7;
  f16 outv[16];
#pragma unroll
  for (int s = 0; s < 4; ++s) {
    float4 acc = {0.f, 0.f, 0.f, 0.f};
#pragma unroll
    for (int kc = 0; kc < 16; ++kc) {
      float4 v = *(const float4*)(P2 + (size_t)((kc << 2) + s) * 65536 + b * 512 + og * 4);
      acc.x += v.x; acc.y += v.y; acc.z += v.z; acc.w += v.w;
    }
    outv[0 * 4 + s] = (f16)fmaxf(acc.x * 0.011048543456039805f, 0.f);  // 1/sqrt(8192)
    outv[1 * 4 + s] = (f16)fmaxf(acc.y * 0.011048543456039805f, 0.f);
    outv[2 * 4 + s] = (f16)fmaxf(acc.z * 0.011048543456039805f, 0.f);
    outv[3 * 4 + s] = (f16)fmaxf(acc.w * 0.011048543456039805f, 0.f);
  }
  f16* dst = A3 + (size_t)b * 2048 + og * 16;
  *(half8*)dst = *(half8*)&outv[0];
  *(half8*)(dst + 8) = *(half8*)&outv[8];
}

__global__ __launch_bounds__(256) void out_fused(const float* __restrict__ P3,
                                                 const float* __restrict__ beta,
                                                 float* __restrict__ out) {
  const int b = blockIdx.x, t = threadIdx.x;
  float acc = 0.f;
#pragma unroll
  for (int oi = 0; oi < 2; ++oi) {
    int o = (oi << 8) + t;
    float v = 0.f;
#pragma unroll
    for (int kc = 0; kc < 16; ++kc) v += P3[(size_t)kc * 65536 + b * 512 + o];
    acc += fmaxf(v * 0.022097086912079608f, 0.f) * beta[o];  // 1/sqrt(2048)
  }
  __shared__ float red[4];
#pragma unroll
  for (int off = 32; off > 0; off >>= 1) acc += __shfl_down(acc, off);
  if ((t & 63) == 0) red[t >> 6] = acc;
  __syncthreads();
  if (t == 0) out[b] = (red[0] + red[1] + red[2] + red[3]) * 0.044194173824159216f;
}

extern "C" void kernel_launch(void* const* d_in, const int* in_sizes, int n_in,
                              void* d_out, int out_size, void* d_ws, size_t ws_size,
                              hipStream_t stream) {
  const float* x    = (const float*)d_in[0];
  const float* w1   = (const float*)d_in[1];
  const float* w2   = (const float*)d_in[2];
  const float* w3   = (const float*)d_in[3];
  const float* beta = (const float*)d_in[4];
  float* out = (float*)d_out;

  char* wsb = (char*)d_ws;
  f16*   A2 = (f16*)wsb;                          // 8 MiB: 4*128*8192 fp16
  float* P2 = (float*)(wsb + (8ull << 20));       // 16 MiB: 64*128*512 fp32
  f16*   A3 = (f16*)(wsb + (24ull << 20));        // 0.5 MiB
  float* P3 = (float*)(wsb + (24ull << 20) + (1ull << 19));  // 4 MiB

  l1_mfma<<<dim3(8, 4, 2), 256, 0, stream>>>(x, w1, A2);
  gemm_f16<0><<<512, 256, 0, stream>>>(A2, w2, P2);
  reduce2<<<64, 256, 0, stream>>>(P2, A3);
  gemm_f16<1><<<128, 256, 0, stream>>>(A3, w3, P3);
  out_fused<<<128, 256, 0, stream>>>(P3, beta, out);
}

// Round 12
// 49.443 us; speedup vs baseline: 1.6225x; 1.6225x over previous
//
#include <hip/hip_runtime.h>

// LocNet2d on MFMA fp16.
// L1 (v3): block = 32b x 32o x one s2-cell x all 16 patches. Xs/Ws staged once as
//   [row][g*64+k48] (k=c*16+f, 48..63 zero-padded); 4 waves, no inner barriers;
//   each thread holds 16 g-values per (b,o) -> native 32-B coalesced A2 stores.
// L2: per-s GEMM M=128,N=512,K=8192, splitK=16, K-step=64, LDS dbuf, vmcnt(8),
//     global_load_lds with source-folded s-gather + bank swizzle (R8 config).
// reduce2: float4 over (kc,s), coalesced 32-B A3 writes.
// L3: same gemm structure, K=2048, splitK=16 -> P3 -> fused reduce+head.

typedef _Float16 f16;
typedef _Float16 half8 __attribute__((ext_vector_type(8)));
typedef _Float16 half4 __attribute__((ext_vector_type(4)));
typedef float f32x4 __attribute__((ext_vector_type(4)));

#define SWZ(r, c) ((((r) << 6) + (c)) ^ (((r) & 7) << 3))
// 1024-half rows (2 KB): XOR 16-B-granule bits with row&7
#define SWZL(r, c) ((((r) << 10) + (c)) ^ (((r) & 7) << 3))

#define GLOAD_LDS16(G, L)                                                     \
  __builtin_amdgcn_global_load_lds(                                           \
      (const __attribute__((address_space(1))) void*)(G),                     \
      (__attribute__((address_space(3))) void*)(L), 16, 0, 0)

__global__ __launch_bounds__(256) void l1_mfma(const float* __restrict__ x,
                                               const float* __restrict__ w1,
                                               f16* __restrict__ A2) {
  // grid (16 o-tiles, 4 s2, 4 b-tiles); block 256 = 4 waves = 2b x 2o quadrants.
  const int o0 = blockIdx.x << 5;
  const int s2 = blockIdx.y;
  const int b0 = blockIdx.z << 5;
  const int p2 = s2 >> 1, q2 = s2 & 1;
  __shared__ __align__(16) f16 Xs[32 * 1024];  // 64 KB: [b][g*64 + c*16 + f]
  __shared__ __align__(16) f16 Ws[32 * 1024];  // 64 KB: [o][g*64 + c*16 + f]
  const int t = threadIdx.x;

  // zero the k=48..63 pads (16 halves per (row,g))
#pragma unroll
  for (int i = 0; i < 8; ++i) {
    int e = (i << 8) + t;
    int row = e >> 6, rem = e & 63, g = rem >> 2, j = rem & 3;
    half4 z = {};
    *(half4*)&Xs[SWZL(row, g * 64 + 48 + j * 4)] = z;
    *(half4*)&Ws[SWZL(row, g * 64 + 48 + j * 4)] = z;
  }
  // stage X: region element (b, c, a, fi, bq, fj0..3) -> Xs[b][(a*4+bq)*64 + c*16 + fi*4]
#pragma unroll
  for (int i = 0; i < 24; ++i) {
    int fl = (i << 8) + t;
    int b = fl / 192, rem = fl % 192;
    int c = rem >> 6, rem2 = rem & 63;
    int a = rem2 >> 4, fi = (rem2 >> 2) & 3, bq = rem2 & 3;
    float4 v = *(const float4*)(x + ((size_t)(b0 + b) * 3 + c) * 1024 +
                                (p2 * 16 + a * 4 + fi) * 32 + q2 * 16 + bq * 4);
    half4 h;
    h[0] = (f16)v.x; h[1] = (f16)v.y; h[2] = (f16)v.z; h[3] = (f16)v.w;
    *(half4*)&Xs[SWZL(b, (a * 4 + bq) * 64 + c * 16 + fi * 4)] = h;
  }
  // stage W: w1[o][c][p1][q1][f] -> Ws[o][g*64 + c*16 + f]
#pragma unroll
  for (int i = 0; i < 24; ++i) {
    int fl = (i << 8) + t;
    int o = fl / 192, rem = fl % 192;
    int c = rem >> 6, rem2 = rem & 63;
    int g = rem2 >> 2, f4 = rem2 & 3;
    float4 v = *(const float4*)(w1 + (size_t)(o0 + o) * 3072 + c * 1024 +
                                (p2 * 4 + (g >> 2)) * 128 + (q2 * 4 + (g & 3)) * 16 + f4 * 4);
    half4 h;
    h[0] = (f16)v.x; h[1] = (f16)v.y; h[2] = (f16)v.z; h[3] = (f16)v.w;
    *(half4*)&Ws[SWZL(o, g * 64 + c * 16 + f4 * 4)] = h;
  }
  __syncthreads();

  const int wv = t >> 6, ln = t & 63;
  const int bw = wv >> 1, ow = wv & 1;
  const int frow = ln & 15, fr4 = ln >> 4;
  f32x4 acc[16] = {};
#pragma unroll
  for (int g = 0; g < 16; ++g) {
#pragma unroll
    for (int ks = 0; ks < 2; ++ks) {
      half8 a = *(const half8*)&Xs[SWZL(bw * 16 + frow, g * 64 + ks * 32 + fr4 * 8)];
      half8 b = *(const half8*)&Ws[SWZL(ow * 16 + frow, g * 64 + ks * 32 + fr4 * 8)];
      acc[g] = __builtin_amdgcn_mfma_f32_16x16x32_f16(a, b, acc[g], 0, 0, 0);
    }
  }
  // store: thread owns (b, o) x 16 g -> one 32-B contiguous chunk each
  f16* A2b = A2 + (size_t)s2 * 128 * 8192;
#pragma unroll
  for (int r = 0; r < 4; ++r) {
    int b = b0 + bw * 16 + fr4 * 4 + r;
    int o = o0 + ow * 16 + frow;
    f16 tmp[16];
#pragma unroll
    for (int g = 0; g < 16; ++g)
      tmp[g] = (f16)fmaxf(acc[g][r] * 0.14433756729740643f, 0.f);  // 1/sqrt(48)
    f16* dst = A2b + (size_t)b * 8192 + o * 16;
    *(half8*)dst = *(half8*)&tmp[0];
    *(half8*)(dst + 8) = *(half8*)&tmp[8];
  }
}

// MODE 0: L2 (w2 fp32 s-gather, 512 blocks). MODE 1: L3 (w3 fp32 contiguous, 128 blocks).
// Tile M=128 x N=64, K-step 64, double-buffered LDS, counted-vmcnt pipeline. (R8 config)
template <int MODE>
__global__ __launch_bounds__(256) void gemm_f16(const f16* __restrict__ A,
                                                const float* __restrict__ W,
                                                float* __restrict__ P) {
  __shared__ __align__(16) f16 As[2][128 * 64];   // 2 x 16 KB
  __shared__ __align__(16) float Bs[2][64 * 64];  // 2 x 16 KB
  const int t = threadIdx.x;
  const int bid = blockIdx.x;
  constexpr int AK = (MODE == 0) ? 8192 : 2048;
  constexpr int ITERS = (MODE == 0) ? 8 : 2;  // K-chunk 512 / 128, step 64
  // MODE 0: bid = s*128 + kc*8 + n. MODE 1: bid = kc*8 + n.
  const int s = (MODE == 0) ? (bid >> 7) : 0;
  const int kc = (MODE == 0) ? ((bid >> 3) & 15) : (bid >> 3);
  const int n = bid & 7;
  const int kb0 = kc * (ITERS * 64);
  const f16* Ab = A + (size_t)(MODE == 0 ? s * 128 : 0) * AK + kb0;
  const int o0 = n << 6;

  const int wv = t >> 6, ln = t & 63;
  const int a_r = (ln >> 3), a_sg0 = ln & 7;
  const int b_r = (ln >> 4), b_sg0 = ln & 15;

#define STAGE(IT, BUF)                                                          \
  {                                                                             \
    _Pragma("unroll") for (int jj = 0; jj < 4; ++jj) {                          \
      int rbase = wv * 32 + jj * 8;                                             \
      int r = rbase + a_r;                                                      \
      int sg = a_sg0 ^ (r & 7);                                                 \
      GLOAD_LDS16(Ab + (size_t)r * AK + ((IT) << 6) + (sg << 3),                \
                  &As[BUF][rbase << 6]);                                        \
    }                                                                           \
    _Pragma("unroll") for (int jj = 0; jj < 4; ++jj) {                          \
      int rbase = wv * 16 + jj * 4;                                             \
      int r = rbase + b_r;                                                      \
      int sg = b_sg0 ^ (r & 7);                                                 \
      const float* gp;                                                          \
      if constexpr (MODE == 0) {                                                \
        int k = kb0 + ((IT) << 6) + (sg << 2);                                  \
        gp = W + (size_t)(o0 + r) * 32768 + ((k >> 4) << 6) + (s << 4) + (k & 15); \
      } else {                                                                  \
        gp = W + (size_t)(o0 + r) * 2048 + kb0 + ((IT) << 6) + (sg << 2);       \
      }                                                                         \
      GLOAD_LDS16(gp, &Bs[BUF][rbase << 6]);                                    \
    }                                                                           \
  }

  const int wr = wv >> 1, wc = wv & 1;
  const int frow = ln & 15, fr4 = ln >> 4;
  f32x4 acc[4][2] = {};

#define COMPUTE(BUF)                                                            \
  _Pragma("unroll") for (int ks = 0; ks < 2; ++ks) {                            \
    half8 a[4];                                                                 \
    _Pragma("unroll") for (int mi = 0; mi < 4; ++mi) {                          \
      int r = wr * 64 + mi * 16 + frow;                                         \
      int gl = ((ks << 2) + fr4) ^ (r & 7);                                     \
      a[mi] = *(const half8*)&As[BUF][(r << 6) + (gl << 3)];                    \
    }                                                                           \
    _Pragma("unroll") for (int ni = 0; ni < 2; ++ni) {                          \
      int r = wc * 32 + ni * 16 + frow;                                         \
      int s0 = (ks << 3) + (fr4 << 1);                                          \
      float4 f0 = *(const float4*)&Bs[BUF][(r << 6) + ((s0 ^ (r & 7)) << 2)];   \
      float4 f1 = *(const float4*)&Bs[BUF][(r << 6) + (((s0 + 1) ^ (r & 7)) << 2)]; \
      half8 hb;                                                                 \
      hb[0] = (f16)f0.x; hb[1] = (f16)f0.y; hb[2] = (f16)f0.z; hb[3] = (f16)f0.w; \
      hb[4] = (f16)f1.x; hb[5] = (f16)f1.y; hb[6] = (f16)f1.z; hb[7] = (f16)f1.w; \
      _Pragma("unroll") for (int mi = 0; mi < 4; ++mi)                          \
        acc[mi][ni] = __builtin_amdgcn_mfma_f32_16x16x32_f16(a[mi], hb, acc[mi][ni], 0, 0, 0); \
    }                                                                           \
  }

  STAGE(0, 0)
#pragma unroll
  for (int it = 0; it < ITERS; ++it) {
    const int cur = it & 1;
    if (it + 1 < ITERS) {
      STAGE(it + 1, cur ^ 1)  // 8 more in flight (16 total)
      asm volatile("s_waitcnt vmcnt(8)" ::: "memory");  // cur's 8 landed
    } else {
      asm volatile("s_waitcnt vmcnt(0)" ::: "memory");  // last tile: full drain
    }
    __builtin_amdgcn_s_barrier();       // all waves see cur tile in LDS
    __builtin_amdgcn_sched_barrier(0);  // rule 18: no hoist above the wait
    COMPUTE(cur)
    __builtin_amdgcn_sched_barrier(0);
    __builtin_amdgcn_s_barrier();       // all reads done before cur is re-staged
  }

  float* Pb = P + (size_t)(MODE == 0 ? (kc << 2) + s : kc) * 65536;
#pragma unroll
  for (int mi = 0; mi < 4; ++mi)
#pragma unroll
    for (int ni = 0; ni < 2; ++ni)
#pragma unroll
      for (int r = 0; r < 4; ++r) {
        int gm = wr * 64 + mi * 16 + fr4 * 4 + r;
        int gn = o0 + wc * 32 + ni * 16 + frow;
        Pb[(size_t)gm * 512 + gn] = acc[mi][ni][r];
      }
#undef STAGE
#undef COMPUTE
}

__global__ __launch_bounds__(256) void reduce2(const float* __restrict__ P2,
                                               f16* __restrict__ A3) {
  // 16384 threads: thread -> (b, og); handles 4 o x 4 s -> one 32-B A3 chunk.
  int idx = blockIdx.x * 256 + threadIdx.x;
  int og = idx & 127, b = idx >> 7;
  f16 outv[16];
#pragma unroll
  for (int s = 0; s < 4; ++s) {
    float4 acc = {0.f, 0.f, 0.f, 0.f};
#pragma unroll
    for (int kc = 0; kc < 16; ++kc) {
      float4 v = *(const float4*)(P2 + (size_t)((kc << 2) + s) * 65536 + b * 512 + og * 4);
      acc.x += v.x; acc.y += v.y; acc.z += v.z; acc.w += v.w;
    }
    outv[0 * 4 + s] = (f16)fmaxf(acc.x * 0.011048543456039805f, 0.f);  // 1/sqrt(8192)
    outv[1 * 4 + s] = (f16)fmaxf(acc.y * 0.011048543456039805f, 0.f);
    outv[2 * 4 + s] = (f16)fmaxf(acc.z * 0.011048543456039805f, 0.f);
    outv[3 * 4 + s] = (f16)fmaxf(acc.w * 0.011048543456039805f, 0.f);
  }
  f16* dst = A3 + (size_t)b * 2048 + og * 16;
  *(half8*)dst = *(half8*)&outv[0];
  *(half8*)(dst + 8) = *(half8*)&outv[8];
}

__global__ __launch_bounds__(256) void out_fused(const float* __restrict__ P3,
                                                 const float* __restrict__ beta,
                                                 float* __restrict__ out) {
  const int b = blockIdx.x, t = threadIdx.x;
  float acc = 0.f;
#pragma unroll
  for (int oi = 0; oi < 2; ++oi) {
    int o = (oi << 8) + t;
    float v = 0.f;
#pragma unroll
    for (int kc = 0; kc < 16; ++kc) v += P3[(size_t)kc * 65536 + b * 512 + o];
    acc += fmaxf(v * 0.022097086912079608f, 0.f) * beta[o];  // 1/sqrt(2048)
  }
  __shared__ float red[4];
#pragma unroll
  for (int off = 32; off > 0; off >>= 1) acc += __shfl_down(acc, off);
  if ((t & 63) == 0) red[t >> 6] = acc;
  __syncthreads();
  if (t == 0) out[b] = (red[0] + red[1] + red[2] + red[3]) * 0.044194173824159216f;
}

extern "C" void kernel_launch(void* const* d_in, const int* in_sizes, int n_in,
                              void* d_out, int out_size, void* d_ws, size_t ws_size,
                              hipStream_t stream) {
  const float* x    = (const float*)d_in[0];
  const float* w1   = (const float*)d_in[1];
  const float* w2   = (const float*)d_in[2];
  const float* w3   = (const float*)d_in[3];
  const float* beta = (const float*)d_in[4];
  float* out = (float*)d_out;

  char* wsb = (char*)d_ws;
  f16*   A2 = (f16*)wsb;                          // 8 MiB: 4*128*8192 fp16
  float* P2 = (float*)(wsb + (8ull << 20));       // 16 MiB: 64*128*512 fp32
  f16*   A3 = (f16*)(wsb + (24ull << 20));        // 0.5 MiB
  float* P3 = (float*)(wsb + (24ull << 20) + (1ull << 19));  // 4 MiB

  l1_mfma<<<dim3(16, 4, 4), 256, 0, stream>>>(x, w1, A2);
  gemm_f16<0><<<512, 256, 0, stream>>>(A2, w2, P2);
  reduce2<<<64, 256, 0, stream>>>(P2, A3);
  gemm_f16<1><<<128, 256, 0, stream>>>(A3, w3, P3);
  out_fused<<<128, 256, 0, stream>>>(P3, beta, out);
}